// Round 14
// baseline (602.594 us; speedup 1.0000x reference)
//
#include <hip/hip_runtime.h>
#include <hip/hip_bf16.h>

// BSpline basis expansion: N = 2097152 points, 64 cubic B-spline columns,
// uniform knots linspace(-1,1,68), degree 3. Output (N,64) FP32 row-major.
//
// Math (audited vs Cox-de Boor incl. both edge truncations): uniform
// unclamped knots => col j is the cardinal cubic B-spline. Only cols
// i-3..i nonzero, i = floor((x+1)*33.5), t = s - i:
//   w0=(1-t)^3/6, w1=(3t^3-6t^2+4)/6, w2=(-3t^3+3t^2+3t+1)/6, w3=t^3/6.
//
// R14 THEORY REWRITE. R13's compile error surfaced the build pipeline:
// source IS compiled fresh each round (hipcc assert at test line 338),
// so R1-R12 DID run — the "stale cache" theory was wrong. The real bug:
// absmax==max|bf16(ref)| is a SATURATING error (any layout/packing/dtype
// mistake yields it, since some position always has ref=max, act=0), and
// the single consistent assignment across all rounds is:
//   input  = bf16 (=> _any_bf16, bf16-rounded ref: 0.66796875 != fp32 max)
//   output = FP32 (reference returns jnp.float32; template: "else float*").
// Every R1-R12 kernel wrote bf16 into the fp32 buffer -> upper half zero
// -> saturated error, identical every round. Fix: fp32 stores.
//
// Design: one thread per float4 (4 cols, 16B), 16 threads/row, coalesced;
// 512 MiB write + ~4 MiB read => ~82 us floor at 6.3 TB/s achievable.
// Input dtype still runtime-sniffed (bf16 vs fp32 both handled; fp32
// viewed as bf16 shows |v|>1/NaN in first 64 halfwords w.p. 1-2^-32).

__device__ __forceinline__ float bf16bits_to_f32(unsigned short h) {
    union { unsigned int u; float f; } c;
    c.u = ((unsigned int)h) << 16;
    return c.f;
}

__global__ __launch_bounds__(256) void BSpline_16466904613521_kernel(
        const void* __restrict__ x_in, float4* __restrict__ out, int n_rows) {
    // --- per-block input-dtype sniff on the first 64 halfwords ---
    __shared__ int s_is_f32;
    if (threadIdx.x == 0) s_is_f32 = 0;
    __syncthreads();
    if (threadIdx.x < 64) {
        float v = bf16bits_to_f32(((const unsigned short*)x_in)[threadIdx.x]);
        if (!(v == v) || fabsf(v) > 1.0f) s_is_f32 = 1;  // benign same-value race
    }
    __syncthreads();

    int tid = blockIdx.x * blockDim.x + threadIdx.x;
    int row = tid >> 4;  // 16 segments of 4 fp32 cols per 64-col row
    int seg = tid & 15;
    if (row >= n_rows) return;

    float x;
    if (s_is_f32) {  // wave-uniform branch
        x = ((const float*)x_in)[row];
    } else {
        x = bf16bits_to_f32(((const unsigned short*)x_in)[row]);
    }
    x = fminf(fmaxf(x, -1.0f), 0.99999988f);  // clip(DMIN, DMAX-1e-7)

    float s = (x + 1.0f) * 33.5f;  // 1/h = 67/2
    int i = (int)floorf(s);
    i = i < 0 ? 0 : (i > 66 ? 66 : i);
    float t = s - (float)i;

    float t2 = t * t;
    float t3 = t2 * t;
    float omt = 1.0f - t;
    float w0 = (omt * omt * omt) * (1.0f / 6.0f);
    float w1 = (3.0f * t3 - 6.0f * t2 + 4.0f) * (1.0f / 6.0f);
    float w2 = (-3.0f * t3 + 3.0f * t2 + 3.0f * t + 1.0f) * (1.0f / 6.0f);
    float w3 = t3 * (1.0f / 6.0f);

    int base = i - 3;   // column receiving w0
    int c0 = seg << 2;  // first column of this thread's 4-col segment

    float v[4];
#pragma unroll
    for (int k = 0; k < 4; ++k) {
        int d = c0 + k - base;  // column c holds weight index c-base
        v[k] = (d == 0) ? w0 : (d == 1) ? w1 : (d == 2) ? w2
                                          : (d == 3) ? w3 : 0.0f;
    }

    float4 o;
    o.x = v[0];
    o.y = v[1];
    o.z = v[2];
    o.w = v[3];
    out[tid] = o;
}

extern "C"
__attribute__((visibility("default")))
void kernel_launch(void* const* d_in, const int* in_sizes, int n_in,
                   void* d_out, int out_size, void* d_ws, size_t ws_size,
                   hipStream_t stream) {
    (void)in_sizes; (void)n_in; (void)d_ws; (void)ws_size;
    const void* x = d_in[0];
    int n_rows = out_size >> 6;          // output is (N,64); out_size = N*64
    int n_threads = n_rows * 16;         // one thread per 16B (4 fp32 cols)
    int block = 256;
    int grid = (n_threads + block - 1) / block;  // 131,072 blocks

    (void)hipGetLastError();  // clear sticky errors
    BSpline_16466904613521_kernel<<<grid, block, 0, stream>>>(
        x, (float4*)d_out, n_rows);
    hipError_t err = hipGetLastError();
    if (err != hipSuccess) {
        // Diagnostic sentinel: reported launch failure -> flood output with
        // 0x7F bytes (3.39e38 fp32) so the failure mode is visible in absmax.
        (void)hipMemsetAsync(d_out, 0x7F, (size_t)out_size * 4u, stream);
    }
}

// Round 16
// 572.830 us; speedup vs baseline: 1.0520x; 1.0520x over previous
//
#include <hip/hip_runtime.h>
#include <hip/hip_bf16.h>

// BSpline basis expansion: N = 2097152 points, 64 cubic B-spline columns,
// uniform knots linspace(-1,1,68), degree 3. Output (N,64) FP32 row-major.
// PASSED R14: absmax 0.00390625, dur_us 602.6.
//
// Math: uniform unclamped knots => col j is the cardinal cubic B-spline.
// Only cols i-3..i nonzero, i = floor((x+1)*33.5), t = s - i:
//   w0=(1-t)^3/6, w1=(3t^3-6t^2+4)/6, w2=(-3t^3+3t^2+3t+1)/6, w3=t^3/6.
//
// R16 = R15 theory with the compile fix: __builtin_nontemporal_store
// requires a clang ext_vector_type, not HIP's float4 class. Theory
// (untested, carried over): 512 MiB streaming write >> 32 MiB L2, default
// write-allocate churns L2; harness fills demonstrate 6.24-6.36 TB/s
// achievable. NT stores bypass L2; sniff hoisted to 1-block pre-kernel
// (flag in d_ws, rewritten every call, capture-safe).

typedef float v4f __attribute__((ext_vector_type(4)));

__device__ __forceinline__ float bf16bits_to_f32(unsigned short h) {
    union { unsigned int u; float f; } c;
    c.u = ((unsigned int)h) << 16;
    return c.f;
}

// 1-block pre-kernel: sniff input dtype from the first 64 halfwords.
// fp32 data viewed as bf16 shows |v|>1 or NaN w.p. 1-2^-32; genuine bf16
// uniform(-1,1) never does.
__global__ void BSpline_16466904613521_sniff(
        const unsigned short* __restrict__ x_u16, int* __restrict__ flag) {
    float v = bf16bits_to_f32(x_u16[threadIdx.x & 63]);
    bool implausible = !(v == v) || fabsf(v) > 1.0f;
    unsigned long long any = __ballot(implausible);
    if (threadIdx.x == 0) flag[0] = (any != 0ull) ? 1 : 0;
}

__global__ __launch_bounds__(256) void BSpline_16466904613521_kernel(
        const void* __restrict__ x_in, v4f* __restrict__ out,
        const int* __restrict__ flag, int n_rows) {
    int tid = blockIdx.x * blockDim.x + threadIdx.x;
    int row = tid >> 4;  // 16 segments of 4 fp32 cols per 64-col row
    int seg = tid & 15;
    if (row >= n_rows) return;

    float x;
    if (flag[0]) {  // wave-uniform branch; flag is L2-hot broadcast
        x = ((const float*)x_in)[row];
    } else {
        x = bf16bits_to_f32(((const unsigned short*)x_in)[row]);
    }
    x = fminf(fmaxf(x, -1.0f), 0.99999988f);  // clip(DMIN, DMAX-1e-7)

    float s = (x + 1.0f) * 33.5f;  // 1/h = 67/2
    int i = (int)floorf(s);
    i = i < 0 ? 0 : (i > 66 ? 66 : i);
    float t = s - (float)i;

    float t2 = t * t;
    float t3 = t2 * t;
    float omt = 1.0f - t;
    float w0 = (omt * omt * omt) * (1.0f / 6.0f);
    float w1 = (3.0f * t3 - 6.0f * t2 + 4.0f) * (1.0f / 6.0f);
    float w2 = (-3.0f * t3 + 3.0f * t2 + 3.0f * t + 1.0f) * (1.0f / 6.0f);
    float w3 = t3 * (1.0f / 6.0f);

    int base = i - 3;   // column receiving w0
    int c0 = seg << 2;  // first column of this thread's 4-col segment

    float v[4];
#pragma unroll
    for (int k = 0; k < 4; ++k) {
        int d = c0 + k - base;  // column c holds weight index c-base
        v[k] = (d == 0) ? w0 : (d == 1) ? w1 : (d == 2) ? w2
                                          : (d == 3) ? w3 : 0.0f;
    }

    v4f o;
    o.x = v[0];
    o.y = v[1];
    o.z = v[2];
    o.w = v[3];
    // Nontemporal: output is streaming write-only (512 MiB >> 32 MiB L2);
    // bypass L2 write-allocate (global_store_dwordx4 nt).
    __builtin_nontemporal_store(o, &out[tid]);
}

extern "C"
__attribute__((visibility("default")))
void kernel_launch(void* const* d_in, const int* in_sizes, int n_in,
                   void* d_out, int out_size, void* d_ws, size_t ws_size,
                   hipStream_t stream) {
    (void)in_sizes; (void)n_in; (void)ws_size;
    const void* x = d_in[0];
    int* flag = (int*)d_ws;              // rewritten every call (capture-safe)
    int n_rows = out_size >> 6;          // output is (N,64); out_size = N*64
    int n_threads = n_rows * 16;         // one thread per 16B (4 fp32 cols)
    int block = 256;
    int grid = (n_threads + block - 1) / block;  // 131,072 blocks

    BSpline_16466904613521_sniff<<<1, 64, 0, stream>>>(
        (const unsigned short*)x, flag);
    BSpline_16466904613521_kernel<<<grid, block, 0, stream>>>(
        x, (v4f*)d_out, flag, n_rows);
}

// Round 17
// 549.984 us; speedup vs baseline: 1.0957x; 1.0415x over previous
//
#include <hip/hip_runtime.h>
#include <hip/hip_bf16.h>

// BSpline basis expansion: N = 2097152 points, 64 cubic B-spline columns,
// uniform knots linspace(-1,1,68), degree 3. Output (N,64) FP32 row-major.
// R14 pass: 602.6 us. R16 (+nt stores, hoisted sniff): 572.8 us.
//
// Math: uniform unclamped knots => col j is the cardinal cubic B-spline.
// Only cols i-3..i nonzero, i = floor((x+1)*33.5), t = s - i:
//   w0=(1-t)^3/6, w1=(3t^3-6t^2+4)/6, w2=(-3t^3+3t^2+3t+1)/6, w3=t^3/6.
//
// R17 theory: timed region = harness fills (~425 us: 2.1 GB ws-poison @
// 6.3 TB/s + 536 MB out-poison) + our share (~145 us vs 85 us floor =
// 536 MB @ fill-demonstrated 6.3 TB/s). Residual attack:
//  (a) separate sniff dispatch (~5-10 us stream-serialized) -> inline at
//      WAVE level (lane reads halfword lane&63, __ballot; no barriers,
//      no d_ws, no extra dispatch);
//  (b) VALU co-dominance (524K waves x ~40 inst x 2 cyc ~ 68 us) -> 8 cols
//      per thread (two nt dwordx4 stores), polynomial computed once per 8
//      cols: ~55 inst/32 B, VALU ~47 us, halves wave count.

typedef float v4f __attribute__((ext_vector_type(4)));

__device__ __forceinline__ float bf16bits_to_f32(unsigned short h) {
    union { unsigned int u; float f; } c;
    c.u = ((unsigned int)h) << 16;
    return c.f;
}

__global__ __launch_bounds__(256) void BSpline_16466904613521_kernel(
        const void* __restrict__ x_in, v4f* __restrict__ out, int n_rows) {
    // --- wave-level input-dtype sniff (no barriers, no extra dispatch) ---
    // fp32 data viewed as bf16 shows |v|>1 or NaN within 64 halfwords
    // w.p. 1-2^-32; genuine bf16 uniform(-1,1) never does. L2-hot load.
    unsigned int lane = threadIdx.x & 63u;
    float sv = bf16bits_to_f32(((const unsigned short*)x_in)[lane]);
    bool implausible = !(sv == sv) || fabsf(sv) > 1.0f;
    const bool is_f32 = (__ballot(implausible) != 0ull);  // wave-uniform

    int tid = blockIdx.x * blockDim.x + threadIdx.x;
    int row = tid >> 3;  // 8 threads per 64-col row (8 cols each)
    int seg = tid & 7;
    if (row >= n_rows) return;

    float x;
    if (is_f32) {  // wave-uniform branch
        x = ((const float*)x_in)[row];
    } else {
        x = bf16bits_to_f32(((const unsigned short*)x_in)[row]);
    }
    x = fminf(fmaxf(x, -1.0f), 0.99999988f);  // clip(DMIN, DMAX-1e-7)

    float s = (x + 1.0f) * 33.5f;  // 1/h = 67/2
    int i = (int)floorf(s);
    i = i < 0 ? 0 : (i > 66 ? 66 : i);
    float t = s - (float)i;

    float t2 = t * t;
    float t3 = t2 * t;
    float omt = 1.0f - t;
    float w0 = (omt * omt * omt) * (1.0f / 6.0f);
    float w1 = (3.0f * t3 - 6.0f * t2 + 4.0f) * (1.0f / 6.0f);
    float w2 = (-3.0f * t3 + 3.0f * t2 + 3.0f * t + 1.0f) * (1.0f / 6.0f);
    float w3 = t3 * (1.0f / 6.0f);

    int base = i - 3;   // column receiving w0
    int c0 = seg << 3;  // first column of this thread's 8-col span

    float v[8];
#pragma unroll
    for (int k = 0; k < 8; ++k) {
        int d = c0 + k - base;  // column c holds weight index c-base
        v[k] = (d == 0) ? w0 : (d == 1) ? w1 : (d == 2) ? w2
                                          : (d == 3) ? w3 : 0.0f;
    }

    v4f o0, o1;
    o0.x = v[0]; o0.y = v[1]; o0.z = v[2]; o0.w = v[3];
    o1.x = v[4]; o1.y = v[5]; o1.z = v[6]; o1.w = v[7];
    // Nontemporal: streaming write-only output (512 MiB >> 32 MiB L2).
    __builtin_nontemporal_store(o0, &out[tid * 2]);
    __builtin_nontemporal_store(o1, &out[tid * 2 + 1]);
}

extern "C"
__attribute__((visibility("default")))
void kernel_launch(void* const* d_in, const int* in_sizes, int n_in,
                   void* d_out, int out_size, void* d_ws, size_t ws_size,
                   hipStream_t stream) {
    (void)in_sizes; (void)n_in; (void)d_ws; (void)ws_size;
    const void* x = d_in[0];
    int n_rows = out_size >> 6;          // output is (N,64); out_size = N*64
    int n_threads = n_rows * 8;          // one thread per 32B (8 fp32 cols)
    int block = 256;
    int grid = (n_threads + block - 1) / block;  // 65,536 blocks

    BSpline_16466904613521_kernel<<<grid, block, 0, stream>>>(
        x, (v4f*)d_out, n_rows);
}

// Round 18
// 542.233 us; speedup vs baseline: 1.1113x; 1.0143x over previous
//
#include <hip/hip_runtime.h>
#include <hip/hip_bf16.h>

// BSpline basis expansion: N = 2097152 points, 64 cubic B-spline columns,
// uniform knots linspace(-1,1,68), degree 3. Output (N,64) FP32 row-major.
// R14: 602.6 -> R16 (+nt, hoisted sniff): 572.8 -> R17 (inline sniff,
// 8 cols/thread): 550.0. Kernel share est. ~123 us vs 85 us floor
// (536 MB @ 6.3 TB/s fill-demonstrated).
//
// Math: uniform unclamped knots => col j is the cardinal cubic B-spline.
// Only cols i-3..i nonzero, i = floor((x+1)*33.5), t = s - i:
//   w0=(1-t)^3/6, w1=(3t^3-6t^2+4)/6, w2=(-3t^3+3t^2+3t+1)/6, w3=t^3/6.
//
// R18 tests H1 (store contiguity): R17's per-thread slot pair {2t, 2t+1}
// makes each wave store instruction write 16 B at 32-B stride (half of
// every 64-B line) — partial-line nt writes are the classic HBM
// efficiency killer. Remap: wave owns a 128-slot (2 KiB) tile T; lane l
// stores slots T+l and T+64+l => both stores are 1 KiB CONTIGUOUS across
// the wave. Cost: lane handles 2 rows (rows 8W+(l>>4) and 8W+4+(l>>4)),
// polynomial evaluated twice (~32 us VALU total, sub-dominant; corrected
// arithmetic: 262K waves x 75 inst x 2 cyc / 1024 SIMDs ~ 16-38K cyc).
// Decode: 520-532 us => H1 confirmed; ~550 => H1 false, test plain
// stores (H5) next; regression => revert layout.

typedef float v4f __attribute__((ext_vector_type(4)));

__device__ __forceinline__ float bf16bits_to_f32(unsigned short h) {
    union { unsigned int u; float f; } c;
    c.u = ((unsigned int)h) << 16;
    return c.f;
}

__device__ __forceinline__ v4f bspline_seg(float x, int q /*0..15*/) {
    // 4-col segment [4q, 4q+3] of the 64-col cardinal cubic basis row.
    x = fminf(fmaxf(x, -1.0f), 0.99999988f);  // clip(DMIN, DMAX-1e-7)
    float s = (x + 1.0f) * 33.5f;             // 1/h = 67/2
    int i = (int)floorf(s);
    i = i < 0 ? 0 : (i > 66 ? 66 : i);
    float t = s - (float)i;

    float t2 = t * t;
    float t3 = t2 * t;
    float omt = 1.0f - t;
    float w0 = (omt * omt * omt) * (1.0f / 6.0f);
    float w1 = (3.0f * t3 - 6.0f * t2 + 4.0f) * (1.0f / 6.0f);
    float w2 = (-3.0f * t3 + 3.0f * t2 + 3.0f * t + 1.0f) * (1.0f / 6.0f);
    float w3 = t3 * (1.0f / 6.0f);

    int base = i - 3;      // column receiving w0
    int c0 = q << 2;       // first column of this 4-col segment
    v4f o;
    float v[4];
#pragma unroll
    for (int k = 0; k < 4; ++k) {
        int d = c0 + k - base;
        v[k] = (d == 0) ? w0 : (d == 1) ? w1 : (d == 2) ? w2
                                          : (d == 3) ? w3 : 0.0f;
    }
    o.x = v[0]; o.y = v[1]; o.z = v[2]; o.w = v[3];
    return o;
}

__global__ __launch_bounds__(256) void BSpline_16466904613521_kernel(
        const void* __restrict__ x_in, v4f* __restrict__ out, int n_slots) {
    // --- wave-level input-dtype sniff (no barriers, no extra dispatch) ---
    unsigned int lane = threadIdx.x & 63u;
    float sv = bf16bits_to_f32(((const unsigned short*)x_in)[lane]);
    bool implausible = !(sv == sv) || fabsf(sv) > 1.0f;
    const bool is_f32 = (__ballot(implausible) != 0ull);  // wave-uniform

    int tid = blockIdx.x * blockDim.x + threadIdx.x;
    // Wave tile: 128 consecutive v4f slots (2 KiB). Lane l -> slots T+l,
    // T+64+l: each wave store instruction is 1 KiB contiguous.
    int s0 = ((tid >> 6) << 7) | (int)lane;
    int s1 = s0 + 64;
    if (s0 >= n_slots) return;

    int q = s0 & 15;          // same 4-col segment index for both slots
    int row_a = s0 >> 4;
    int row_b = s1 >> 4;      // = row_a + 4

    float xa, xb;
    if (is_f32) {  // wave-uniform branch
        xa = ((const float*)x_in)[row_a];
        xb = ((const float*)x_in)[row_b];
    } else {
        xa = bf16bits_to_f32(((const unsigned short*)x_in)[row_a]);
        xb = bf16bits_to_f32(((const unsigned short*)x_in)[row_b]);
    }

    v4f oa = bspline_seg(xa, q);
    v4f ob = bspline_seg(xb, q);

    // Nontemporal: streaming write-only output (512 MiB >> 32 MiB L2).
    __builtin_nontemporal_store(oa, &out[s0]);
    if (s1 < n_slots) __builtin_nontemporal_store(ob, &out[s1]);
}

extern "C"
__attribute__((visibility("default")))
void kernel_launch(void* const* d_in, const int* in_sizes, int n_in,
                   void* d_out, int out_size, void* d_ws, size_t ws_size,
                   hipStream_t stream) {
    (void)in_sizes; (void)n_in; (void)d_ws; (void)ws_size;
    const void* x = d_in[0];
    int n_slots = out_size >> 2;         // total v4f slots = N*64/4 = 33.5M
    int n_threads = n_slots >> 1;        // each thread covers 2 slots
    int block = 256;
    int grid = (n_threads + block - 1) / block;  // 65,536 blocks

    BSpline_16466904613521_kernel<<<grid, block, 0, stream>>>(
        x, (v4f*)d_out, n_slots);
}